// Round 11
// baseline (237.687 us; speedup 1.0000x reference)
//
#include <hip/hip_runtime.h>
#include <hip/hip_fp16.h>
#include <cstddef>

// ---------------------------------------------------------------------------
// CrossAttention, f16 MFMA, round 19.
//   B=2, Sq=Sk=2048, D=1024, H=16, Dh=64
// r18 post-mortem: 16-wave attn null (50.2 vs 46.8) -> chain not binding;
// attn reverted to r16 (best, 46.8us). r19 lever: kernel-time ledger shows
// prep's cvt pass ~11us serial moving 72MB only to cast dtype. Fold it into
// gemm_proj: AF32 path reg-stages A from fp32 (float4 prefetch during MFMA
// section -> cvt RTN -> ds_write_b128), B stays global_load_lds (r16). The
// fp32 prefetch drains at the same barrier as B's gload_lds -> added cost is
// ~16 cvt VALU/thread/K-step only. prep -> wtrans4 only (~3us).
// Layouts (32x32x16): A/B [idx=lane&31][k=(lane>>5)*8+j];
//   C/D col=lane&31, row=(reg&3)+8*(reg>>2)+4*(lane>>5)  [m74/m101].
// P repack: P0=pk(s0,s1) P1=pk(s2,s3) P2=pk(s4,s5) P3=pk(s6,s7);
//   swap(P0,P2), swap(P1,P3) -> B-frag words [P0,P1,P2,P3]. (r13-verified)
// ---------------------------------------------------------------------------

#define B_   2
#define S_   2048
#define D_   1024
#define H_   16
#define DH_  64

typedef _Float16 half8 __attribute__((ext_vector_type(8)));
typedef _Float16 half4 __attribute__((ext_vector_type(4)));
typedef _Float16 half2v __attribute__((ext_vector_type(2)));
typedef float floatx4 __attribute__((ext_vector_type(4)));
typedef float floatx16 __attribute__((ext_vector_type(16)));
typedef int intx4 __attribute__((ext_vector_type(4)));

#define MFMA32(a, b, c) __builtin_amdgcn_mfma_f32_16x16x32_f16((a), (b), (c), 0, 0, 0)
#define MFMA3216(a, b, c) __builtin_amdgcn_mfma_f32_32x32x16_f16((a), (b), (c), 0, 0, 0)

#if __has_builtin(__builtin_amdgcn_fdot2)
#define LP_FDOT2 1
#else
#define LP_FDOT2 0
#endif

#define GLD_AS(p) ((const __attribute__((address_space(1))) void*)(p))
#define LDS_AS(p) ((__attribute__((address_space(3))) void*)(p))

// exchange: newA = {A.lo32, B.lo32}, newB = {A.hi32, B.hi32}
__device__ __forceinline__ void half_swap(int& a, int& b, const int hi) {
#if __has_builtin(__builtin_amdgcn_permlane32_swap)
    (void)hi;
    auto r = __builtin_amdgcn_permlane32_swap(a, b, false, false);
    a = r[0]; b = r[1];
#else
    const int ax = __shfl_xor(a, 32, 64), bx = __shfl_xor(b, 32, 64);
    const int na = hi ? bx : a;
    b = hi ? b : ax;
    a = na;
#endif
}

// ---- W [K][N] fp32 -> Wt [N][K] f16, 64x64 tiles, 4 weights via z ----
__global__ __launch_bounds__(256) void wtrans4(
    const float* __restrict__ Wq, const float* __restrict__ Wk,
    const float* __restrict__ Wv, const float* __restrict__ Wo,
    __half* __restrict__ Wtq, __half* __restrict__ Wtk,
    __half* __restrict__ Wtv, __half* __restrict__ Wto)
{
    __shared__ __align__(16) __half T[64][72];
    const float* Ws[4] = {Wq, Wk, Wv, Wo};
    __half* Wts[4] = {Wtq, Wtk, Wtv, Wto};
    const float* W = Ws[blockIdx.z];
    __half* Wt = Wts[blockIdx.z];
    const int tid = threadIdx.x;
    const int n0 = blockIdx.x * 64, k0 = blockIdx.y * 64;
    #pragma unroll
    for (int p = 0; p < 4; ++p) {
        const int c = tid + p * 256;
        const int kr = c >> 4, nc = (c & 15) * 4;
        const float4 a = *(const float4*)&W[(size_t)(k0 + kr) * D_ + n0 + nc];
        T[nc + 0][kr] = __float2half(a.x);
        T[nc + 1][kr] = __float2half(a.y);
        T[nc + 2][kr] = __float2half(a.z);
        T[nc + 3][kr] = __float2half(a.w);
    }
    __syncthreads();
    #pragma unroll
    for (int p = 0; p < 2; ++p) {
        const int c = tid + p * 256;
        const int nr = c >> 3, kc = (c & 7) * 8;
        *(half8*)&Wt[(size_t)(n0 + nr) * D_ + k0 + kc] = *(const half8*)&T[nr][kc];
    }
}

// ---- 128x128 f16 GEMM core (r16 m97 structure) ----
// AF32=0: A f16 via global_load_lds. AF32=1: A fp32 reg-staged with RTN
// cvt folded in (prefetch flies during prior MFMA section). B always f16
// via global_load_lds. Static LDS 34816B (staging 32KB linear + epilogue
// overlay Ct[128][136]). 2 barriers per K-step.
// mode 0: dst f16 scatter [B,H,S,Dh] * oscale; mode 1: fp32 [M][1024];
// mode 2: f16 transposed [B,H,Dh,S].
template<int AF32>
__device__ __forceinline__ void gemm_core(
    const __half* __restrict__ A, const float* __restrict__ A32,
    const __half* __restrict__ Bt,
    const float* __restrict__ bias, void* __restrict__ dst,
    const int mode, const float oscale, const int m0, const int n0)
{
    __shared__ __align__(16) char gsm[34816];
    __half* Asl = (__half*)gsm;            // [128][64] linear
    __half* Bsl = (__half*)(gsm + 16384);  // [128][64] linear

    const int tid = threadIdx.x;
    const int lane = tid & 63, wv = tid >> 6;
    const int quad = lane >> 4, lr = lane & 15;
    const int wm0 = (wv >> 1) * 64, wn0 = (wv & 1) * 64;

    floatx4 acc[4][4];
    #pragma unroll
    for (int i = 0; i < 4; ++i)
        #pragma unroll
        for (int j = 0; j < 4; ++j)
            acc[i][j] = (floatx4){0.f, 0.f, 0.f, 0.f};

    const int rowb = wv * 32 + (lane >> 3);
    const int colb = (lane & 7) * 8;
    const __half* gA = A  + (size_t)(m0 + rowb) * D_ + colb;
    const __half* gB = Bt + (size_t)(n0 + rowb) * D_ + colb;

    // AF32 reg-staging: slot c = tid + p*256 -> row=c>>3, seg=(c&7)*8
    float4 pa32[4][2];
    if (AF32) {
        #pragma unroll
        for (int p = 0; p < 4; ++p) {
            const int c = tid + p * 256;
            const float* src = A32 + (size_t)(m0 + (c >> 3)) * D_ + (c & 7) * 8;
            pa32[p][0] = *(const float4*)src;
            pa32[p][1] = *(const float4*)(src + 4);
        }
    }

    for (int k0 = 0; k0 < D_; k0 += 64) {
        __syncthreads();                  // prior compute's LDS reads done
        if (AF32) {
            #pragma unroll
            for (int p = 0; p < 4; ++p) {
                const int c = tid + p * 256;
                half8 h;
                h[0] = (_Float16)pa32[p][0].x; h[1] = (_Float16)pa32[p][0].y;
                h[2] = (_Float16)pa32[p][0].z; h[3] = (_Float16)pa32[p][0].w;
                h[4] = (_Float16)pa32[p][1].x; h[5] = (_Float16)pa32[p][1].y;
                h[6] = (_Float16)pa32[p][1].z; h[7] = (_Float16)pa32[p][1].w;
                *(half8*)&Asl[(c >> 3) * 64 + (c & 7) * 8] = h;
            }
        } else {
            #pragma unroll
            for (int p = 0; p < 4; ++p)
                __builtin_amdgcn_global_load_lds(
                    GLD_AS(gA + (size_t)p * 8 * D_),
                    LDS_AS(gsm + (wv * 4 + p) * 1024), 16, 0, 0);
            gA += 64;
        }
        #pragma unroll
        for (int p = 0; p < 4; ++p)
            __builtin_amdgcn_global_load_lds(
                GLD_AS(gB + (size_t)p * 8 * D_),
                LDS_AS(gsm + 16384 + (wv * 4 + p) * 1024), 16, 0, 0);
        gB += 64;
        if (AF32 && k0 + 64 < D_) {       // next A tile; drains with B at bar2
            #pragma unroll
            for (int p = 0; p < 4; ++p) {
                const int c = tid + p * 256;
                const float* src = A32 + (size_t)(m0 + (c >> 3)) * D_
                                       + k0 + 64 + (c & 7) * 8;
                pa32[p][0] = *(const float4*)src;
                pa32[p][1] = *(const float4*)(src + 4);
            }
        }
        __syncthreads();                  // staged tile visible (lgkm+vmcnt)

        __builtin_amdgcn_s_setprio(1);
        #pragma unroll
        for (int ks = 0; ks < 2; ++ks) {
            const int ko = quad * 8 + ks * 32;
            half8 af[4], bf[4];
            #pragma unroll
            for (int i = 0; i < 4; ++i)
                af[i] = *(const half8*)&Asl[(wm0 + i * 16 + lr) * 64 + ko];
            #pragma unroll
            for (int j = 0; j < 4; ++j)
                bf[j] = *(const half8*)&Bsl[(wn0 + j * 16 + lr) * 64 + ko];
            #pragma unroll
            for (int i = 0; i < 4; ++i)
                #pragma unroll
                for (int j = 0; j < 4; ++j)
                    acc[i][j] = MFMA32(af[i], bf[j], acc[i][j]);
        }
        __builtin_amdgcn_s_setprio(0);
    }

    if (mode == 1) {
        float* out = (float*)dst;
        #pragma unroll
        for (int i = 0; i < 4; ++i) {
            #pragma unroll
            for (int j = 0; j < 4; ++j) {
                const int col = n0 + wn0 + j * 16 + lr;
                const float bval = bias[col];
                #pragma unroll
                for (int r = 0; r < 4; ++r) {
                    const int m = m0 + wm0 + i * 16 + quad * 4 + r;
                    out[(size_t)m * D_ + col] = acc[i][j][r] + bval;
                }
            }
        }
        return;
    }

    // ---- LDS transpose epilogue (modes 0 and 2) ----
    __syncthreads();                      // all waves' staging reads done
    __half (*Ct)[136] = (__half(*)[136])gsm;
    #pragma unroll
    for (int i = 0; i < 4; ++i) {
        #pragma unroll
        for (int j = 0; j < 4; ++j) {
            const int nl = wn0 + j * 16 + lr;
            const float bval = bias[n0 + nl];
            #pragma unroll
            for (int r = 0; r < 4; ++r) {
                const int ml = wm0 + i * 16 + quad * 4 + r;
                const _Float16 hv = (_Float16)((acc[i][j][r] + bval) * oscale);
                if (mode == 0) Ct[ml][nl] = hv;
                else           Ct[nl][ml] = hv;
            }
        }
    }
    __syncthreads();
    __half* oh = (__half*)dst;
    #pragma unroll
    for (int p = 0; p < 8; ++p) {
        const int row = (tid >> 4) + p * 16;
        const int cs  = (tid & 15) * 8;
        const half8 vls = *(const half8*)&Ct[row][cs];
        if (mode == 0) {
            const int m = m0 + row, col = n0 + cs;
            const int b = m >> 11, s = m & (S_ - 1);
            const int h = col >> 6, d = col & 63;
            *(half8*)&oh[(((size_t)(b * H_ + h) * S_ + s) << 6) + d] = vls;
        } else {
            const int col = n0 + row, m = m0 + cs;
            const int b = m >> 11, s = m & (S_ - 1);
            const int h = col >> 6, d = col & 63;
            *(half8*)&oh[((size_t)(b * H_ + h) * DH_ + d) * S_ + s] = vls;
        }
    }
}

// z=0: Q (scatter, *0.125*log2e for exp2 softmax), z=1: K, z=2: V (transposed)
// A = raw fp32 q/k/v (cvt folded into staging). XCD swizzle: 768 blocks,
// 96/XCD contiguous (bijective).
__global__ __launch_bounds__(256) void gemm_proj(
    const float* __restrict__ q, const float* __restrict__ k,
    const float* __restrict__ v,
    const __half* __restrict__ Wtq, const __half* __restrict__ Wtk,
    const __half* __restrict__ Wtv,
    const float* __restrict__ bq, const float* __restrict__ bk,
    const float* __restrict__ bv,
    __half* __restrict__ qhf, __half* __restrict__ khf, __half* __restrict__ vht)
{
    const int flat = blockIdx.x + (blockIdx.y << 3) + (blockIdx.z << 8);
    const int wid = (flat & 7) * 96 + (flat >> 3);
    const int z = wid >> 8;
    const int rem = wid & 255;
    const int m0 = (rem >> 3) * 128, n0 = (rem & 7) * 128;

    const float* As32[3] = {q, k, v};
    const __half* Bts[3] = {Wtq, Wtk, Wtv};
    const float* bs[3] = {bq, bk, bv};
    __half* ds[3] = {qhf, khf, vht};
    gemm_core<1>(nullptr, As32[z], Bts[z], bs[z], ds[z], z == 2 ? 2 : 0,
                 z == 0 ? 0.1803368801111244f : 1.0f, m0, n0);
}

// XCD swizzle: grid (8,32)=256 blocks, 32/XCD contiguous.
__global__ __launch_bounds__(256) void gemm_final(
    const __half* __restrict__ attf, const __half* __restrict__ Wto,
    const float* __restrict__ bo, float* __restrict__ out)
{
    const int flat = blockIdx.x + (blockIdx.y << 3);
    const int wid = (flat & 7) * 32 + (flat >> 3);
    const int m0 = (wid >> 3) * 128, n0 = (wid & 7) * 128;
    gemm_core<0>(attf, nullptr, Wto, bo, out, 1, 1.0f, m0, n0);
}

// ---- flash attention (r16 structure, best measured 46.8us) ----
// 32x32 MFMA, QBLK=128, 512 threads (8 waves = 2 kb x 4 qb), KVBLK=64,
// double-buffered LDS. qhf/khf: [B,H,S,64] f16 (Q pre-scaled 0.125*log2e).
// vht: [B,H,64,S]. XCD swizzle: grid (16,32)=512 blocks, 64/XCD.
__global__ __launch_bounds__(512, 4) void attn_f16(
    const __half* __restrict__ qhf, const __half* __restrict__ khf,
    const __half* __restrict__ vht, __half* __restrict__ attf)
{
    __shared__ __align__(16) char smem[36864];

    const int tid = threadIdx.x;
    const int lane = tid & 63, wv = tid >> 6;
    const int l31 = lane & 31, hi = lane >> 5;
    const int kb = wv >> 2, qb = wv & 3;
    const int flat = blockIdx.x + (blockIdx.y << 4);
    const int wid = ((flat & 7) << 6) + (flat >> 3);
    const int bh = wid >> 4;
    const int q0 = (wid & 15) * 128;
    const size_t hbase = (size_t)bh * S_ * DH_;

    // ---- Q B-frags [idx=q=l31][k(d)=hi*8+j] per 16-d slice, from global ----
    half8 qB[4];
    #pragma unroll
    for (int ds = 0; ds < 4; ++ds)
        qB[ds] = *(const half8*)&qhf[hbase
            + (size_t)(q0 + qb * 32 + l31) * DH_ + ds * 16 + hi * 8];

    float lp0 = 0.f, lp1 = 0.f;
#if !LP_FDOT2
    float lp2 = 0.f, lp3 = 0.f;
#endif
    floatx16 O[2];
    #pragma unroll
    for (int i = 0; i < 16; ++i) { O[0][i] = 0.f; O[1][i] = 0.f; }

    // ---- staging mapping (512 thr): one K + one V half8 per thread ----
    const int srow = tid >> 3, sseg = (tid & 7) * 8;
    const __half* kg = khf + hbase + (size_t)srow * DH_ + sseg;  // += 64*DH_/tile
    const __half* vg = vht + hbase + (size_t)srow * S_ + sseg;   // += 64/tile

    // ---- stage tile 0 directly into buf0 ----
    {
        __half (*K0)[72] = (__half(*)[72])smem;
        __half (*V0)[72] = (__half(*)[72])(smem + 9216);
        *(half8*)&K0[srow][sseg] = *(const half8*)kg;
        *(half8*)&V0[srow][sseg] = *(const half8*)vg;
    }
    // ---- prefetch tile 1 into registers ----
    kg += 64 * DH_; vg += 64;
    half8 pk = *(const half8*)kg;
    half8 pv = *(const half8*)vg;
    __syncthreads();                       // tile 0 visible

    const half2v one2 = {(_Float16)1.0f, (_Float16)1.0f};

    for (int kt = 0; kt < S_; kt += 64) {
        const int cb = (kt >> 6) & 1;
        __half (*Ks)[72] = (__half(*)[72])(smem + cb * 18432);
        __half (*Vs)[72] = (__half(*)[72])(smem + cb * 18432 + 9216);
        __half (*Kn)[72] = (__half(*)[72])(smem + (cb ^ 1) * 18432);
        __half (*Vn)[72] = (__half(*)[72])(smem + (cb ^ 1) * 18432 + 9216);

        // write tile t+1 into the other buffer (overlaps compute reads)
        if (kt + 64 < S_) {
            *(half8*)&Kn[srow][sseg] = pk;
            *(half8*)&Vn[srow][sseg] = pv;
            if (kt + 128 < S_) {           // issue t+2 loads; fly during compute
                kg += 64 * DH_; vg += 64;
                pk = *(const half8*)kg;
                pv = *(const half8*)vg;
            }
        }

        // ---- S^T = K Q^T : 32k (band kb) x 32q (band qb), K-dim = d ----
        floatx16 s;
        #pragma unroll
        for (int i = 0; i < 16; ++i) s[i] = 0.f;
        __builtin_amdgcn_s_setprio(1);
        #pragma unroll
        for (int ds = 0; ds < 4; ++ds) {
            const half8 aK = *(const half8*)&Ks[kb * 32 + l31][ds * 16 + hi * 8];
            s = MFMA3216(aK, qB[ds], s);
        }
        __builtin_amdgcn_s_setprio(0);

        // ---- P^T = exp2(S^T) ----
        #pragma unroll
        for (int r = 0; r < 16; ++r) {
            const float e = __builtin_amdgcn_exp2f(s[r]);
#if !LP_FDOT2
            (r & 2) ? ((r & 1) ? (lp3 += e) : (lp2 += e))
                    : ((r & 1) ? (lp1 += e) : (lp0 += e));
#endif
            s[r] = e;
        }

        // ---- pack to PV B-frags [idx=q][k=hi*8+j] per 16-k slice ----
        half8 pB[2];
        int PW[2][4];
        #pragma unroll
        for (int ks = 0; ks < 2; ++ks) {
            int P0 = __builtin_bit_cast(int, __builtin_amdgcn_cvt_pkrtz(s[ks * 8 + 0], s[ks * 8 + 1]));
            int P1 = __builtin_bit_cast(int, __builtin_amdgcn_cvt_pkrtz(s[ks * 8 + 2], s[ks * 8 + 3]));
            int P2 = __builtin_bit_cast(int, __builtin_amdgcn_cvt_pkrtz(s[ks * 8 + 4], s[ks * 8 + 5]));
            int P3 = __builtin_bit_cast(int, __builtin_amdgcn_cvt_pkrtz(s[ks * 8 + 6], s[ks * 8 + 7]));
            half_swap(P0, P2, hi);
            half_swap(P1, P3, hi);
            PW[ks][0] = P0; PW[ks][1] = P1; PW[ks][2] = P2; PW[ks][3] = P3;
            const intx4 w = {P0, P1, P2, P3};
            pB[ks] = __builtin_bit_cast(half8, w);
        }

        // ---- O^T += V^T P^T over wave's 32-k band ----
        __builtin_amdgcn_s_setprio(1);
        #pragma unroll
        for (int db = 0; db < 2; ++db)
            #pragma unroll
            for (int ks = 0; ks < 2; ++ks) {
                const half8 aV = *(const half8*)&Vs[db * 32 + l31][kb * 32 + ks * 16 + hi * 8];
                O[db] = MFMA3216(aV, pB[ks], O[db]);
            }
        __builtin_amdgcn_s_setprio(0);

#if LP_FDOT2
        // ---- lp row-sum from packed P (MFMA pipe busy window) ----
        #pragma unroll
        for (int ks = 0; ks < 2; ++ks) {
            lp0 = __builtin_amdgcn_fdot2(__builtin_bit_cast(half2v, PW[ks][0]), one2, lp0, false);
            lp1 = __builtin_amdgcn_fdot2(__builtin_bit_cast(half2v, PW[ks][1]), one2, lp1, false);
            lp0 = __builtin_amdgcn_fdot2(__builtin_bit_cast(half2v, PW[ks][2]), one2, lp0, false);
            lp1 = __builtin_amdgcn_fdot2(__builtin_bit_cast(half2v, PW[ks][3]), one2, lp1, false);
        }
#endif

        __syncthreads();   // t+1 writes visible; buf reads done before t+2 overwrite
    }

    // ---- epilogue: 2-way k-band reduce + softmax normalize, 128 q rows ----
    float (*R)[132] = (float(*)[132])smem;            // [64 d][128 q(+4)] f32
    float* Lred = (float*)(smem + 33792);             // [2][128] f32

#if LP_FDOT2
    float lp = lp0 + lp1;
#else
    float lp = (lp0 + lp1) + (lp2 + lp3);
#endif
    lp += __shfl_xor(lp, 32, 64);                     // combine hi/lo (same q)
    const int qg = qb * 32 + l31;
    if (lane < 32) Lred[kb * 128 + qg] = lp;
    if (kb == 1) {
        #pragma unroll
        for (int db = 0; db < 2; ++db)
            #pragma unroll
            for (int r = 0; r < 16; ++r) {
                const int d = db * 32 + (r & 3) + 8 * (r >> 2) + 4 * hi;
                R[d][qg] = O[db][r];
            }
    }
    __syncthreads();
    if (kb == 0) {
        const float il = 1.0f / (Lred[qg] + Lred[128 + qg]);
        #pragma unroll
        for (int db = 0; db < 2; ++db)
            #pragma unroll
            for (int r = 0; r < 16; ++r) {
                const int d = db * 32 + (r & 3) + 8 * (r >> 2) + 4 * hi;
                O[db][r] = (O[db][r] + R[d][qg]) * il;
            }
    }
    __syncthreads();
    __half (*F)[72] = (__half(*)[72])smem;            // [128 q][64 d] f16
    if (kb == 0) {
        #pragma unroll
        for (int db = 0; db < 2; ++db)
            #pragma unroll
            for (int t = 0; t < 4; ++t) {
                half4 hv;
                #pragma unroll
                for (int r = 0; r < 4; ++r) hv[r] = (_Float16)O[db][t * 4 + r];
                *(half4*)&F[qg][db * 32 + t * 8 + hi * 4] = hv;
            }
    }
    __syncthreads();

    const int b = bh >> 4, h = bh & 15;
    const int qrow = tid >> 2, dseg = (tid & 3) * 16;
    __half* dstp = &attf[(((size_t)(b * S_ + q0 + qrow)) << 10) + h * DH_ + dseg];
    *(half8*)&dstp[0] = *(const half8*)&F[qrow][dseg];
    *(half8*)&dstp[8] = *(const half8*)&F[qrow][dseg + 8];
}

extern "C" void kernel_launch(void* const* d_in, const int* in_sizes, int n_in,
                              void* d_out, int out_size, void* d_ws, size_t ws_size,
                              hipStream_t stream) {
    const float* q  = (const float*)d_in[0];
    const float* k  = (const float*)d_in[1];
    const float* v  = (const float*)d_in[2];
    const float* Wq = (const float*)d_in[3];
    const float* bq = (const float*)d_in[4];
    const float* Wk = (const float*)d_in[5];
    const float* bk = (const float*)d_in[6];
    const float* Wv = (const float*)d_in[7];
    const float* bv = (const float*)d_in[8];
    const float* Wo = (const float*)d_in[9];
    const float* bo = (const float*)d_in[10];
    float* out = (float*)d_out;

    __half* ws = (__half*)d_ws;
    const size_t NE = (size_t)B_ * S_ * D_;     // 4,194,304
    __half* qhf  = ws + 3 * NE;
    __half* khf  = ws + 4 * NE;
    __half* vht  = ws + 5 * NE;
    __half* attf = ws + 6 * NE;
    __half* Wtq  = ws + 7 * NE;
    __half* Wtk  = Wtq + (size_t)D_ * D_;
    __half* Wtv  = Wtk + (size_t)D_ * D_;
    __half* Wto  = Wtv + (size_t)D_ * D_;

    const dim3 blk(256);
    wtrans4<<<dim3(16, 16, 4), blk, 0, stream>>>(Wq, Wk, Wv, Wo, Wtq, Wtk, Wtv, Wto);

    gemm_proj<<<dim3(D_ / 128, (B_ * S_) / 128, 3), blk, 0, stream>>>(
        q, k, v, Wtq, Wtk, Wtv, bq, bk, bv, qhf, khf, vht);

    attn_f16<<<dim3(S_ / 128, B_ * H_), dim3(512), 0, stream>>>(qhf, khf, vht, attf);

    gemm_final<<<dim3(D_ / 128, (B_ * S_) / 128), blk, 0, stream>>>(attf, Wto, bo, out);
}

// Round 12
// 225.459 us; speedup vs baseline: 1.0542x; 1.0542x over previous
//
#include <hip/hip_runtime.h>
#include <hip/hip_fp16.h>
#include <cstddef>

// ---------------------------------------------------------------------------
// CrossAttention, f16 MFMA, round 20.
//   B=2, Sq=Sk=2048, D=1024, H=16, Dh=64
// r19 post-mortem: fp32-A fold into gemm_proj regressed (77us, conflicts
// 3.4M->9.7M): ds_write staging + cvt back on critical path. Reverted to the
// r16 configuration (best, 222.36us: prep=cvt3+wtrans, gload_lds gemm core).
// r20 probe: attn staging -> global_load_lds with T21 both-sides swizzle:
// linear 8KB K/V LDS buffers (dbuf 2x16KB), per-lane global src pre-shuffled
// (seg^=row&7, 16B granule), reads XOR the same mask (~4-way conflicts, same
// as the old [72] padding). Removes 16 ds_write_b128/tile/block + prefetch
// VGPR roundtrip. Loads for t+1 issued at loop top, single end barrier.
// Layouts (32x32x16): A/B [idx=lane&31][k=(lane>>5)*8+j];
//   C/D col=lane&31, row=(reg&3)+8*(reg>>2)+4*(lane>>5)  [m74/m101].
// P repack: P0=pk(s0,s1) P1=pk(s2,s3) P2=pk(s4,s5) P3=pk(s6,s7);
//   swap(P0,P2), swap(P1,P3) -> B-frag words [P0,P1,P2,P3]. (r13-verified)
// ---------------------------------------------------------------------------

#define B_   2
#define S_   2048
#define D_   1024
#define H_   16
#define DH_  64

typedef _Float16 half8 __attribute__((ext_vector_type(8)));
typedef _Float16 half4 __attribute__((ext_vector_type(4)));
typedef _Float16 half2v __attribute__((ext_vector_type(2)));
typedef float floatx4 __attribute__((ext_vector_type(4)));
typedef float floatx16 __attribute__((ext_vector_type(16)));
typedef int intx4 __attribute__((ext_vector_type(4)));

#define MFMA32(a, b, c) __builtin_amdgcn_mfma_f32_16x16x32_f16((a), (b), (c), 0, 0, 0)
#define MFMA3216(a, b, c) __builtin_amdgcn_mfma_f32_32x32x16_f16((a), (b), (c), 0, 0, 0)

#if __has_builtin(__builtin_amdgcn_fdot2)
#define LP_FDOT2 1
#else
#define LP_FDOT2 0
#endif

#define GLD_AS(p) ((const __attribute__((address_space(1))) void*)(p))
#define LDS_AS(p) ((__attribute__((address_space(3))) void*)(p))

// exchange: newA = {A.lo32, B.lo32}, newB = {A.hi32, B.hi32}
__device__ __forceinline__ void half_swap(int& a, int& b, const int hi) {
#if __has_builtin(__builtin_amdgcn_permlane32_swap)
    (void)hi;
    auto r = __builtin_amdgcn_permlane32_swap(a, b, false, false);
    a = r[0]; b = r[1];
#else
    const int ax = __shfl_xor(a, 32, 64), bx = __shfl_xor(b, 32, 64);
    const int na = hi ? bx : a;
    b = hi ? b : ax;
    a = na;
#endif
}

// ---- fused: fp32->f16 cvt for q/k/v (z<3) + W transpose x4 (z==3) ----
__global__ __launch_bounds__(256) void prep(
    const float* __restrict__ q, const float* __restrict__ k,
    const float* __restrict__ v,
    __half* __restrict__ qf, __half* __restrict__ kf, __half* __restrict__ vf,
    const float* __restrict__ Wq, const float* __restrict__ Wk,
    const float* __restrict__ Wv, const float* __restrict__ Wo,
    __half* __restrict__ Wtq, __half* __restrict__ Wtk,
    __half* __restrict__ Wtv, __half* __restrict__ Wto)
{
    __shared__ __align__(16) __half T[64][72];
    const int tid = threadIdx.x;
    const int z = blockIdx.z;
    if (z < 3) {
        const float* srcs[3] = {q, k, v};
        __half* dsts[3] = {qf, kf, vf};
        const int i = blockIdx.x * 256 + tid;
        const float4* s = (const float4*)srcs[z];
        const float4 a = s[2 * i], b = s[2 * i + 1];
        half8 h;
        h[0] = (_Float16)a.x; h[1] = (_Float16)a.y; h[2] = (_Float16)a.z; h[3] = (_Float16)a.w;
        h[4] = (_Float16)b.x; h[5] = (_Float16)b.y; h[6] = (_Float16)b.z; h[7] = (_Float16)b.w;
        *(half8*)&dsts[z][(size_t)i * 8] = h;
        return;
    }
    if (blockIdx.x >= 256) return;
    const float* Ws[4] = {Wq, Wk, Wv, Wo};
    __half* Wts[4] = {Wtq, Wtk, Wtv, Wto};
    const int n0 = (blockIdx.x & 15) * 64, k0 = (blockIdx.x >> 4) * 64;
    for (int w = 0; w < 4; ++w) {
        const float* W = Ws[w];
        __half* Wt = Wts[w];
        #pragma unroll
        for (int p = 0; p < 4; ++p) {
            const int c = tid + p * 256;
            const int kr = c >> 4, nc = (c & 15) * 4;
            const float4 a = *(const float4*)&W[(size_t)(k0 + kr) * D_ + n0 + nc];
            T[nc + 0][kr] = __float2half(a.x);
            T[nc + 1][kr] = __float2half(a.y);
            T[nc + 2][kr] = __float2half(a.z);
            T[nc + 3][kr] = __float2half(a.w);
        }
        __syncthreads();
        #pragma unroll
        for (int p = 0; p < 2; ++p) {
            const int c = tid + p * 256;
            const int nr = c >> 3, kc = (c & 7) * 8;
            *(half8*)&Wt[(size_t)(n0 + nr) * D_ + k0 + kc] = *(const half8*)&T[nr][kc];
        }
        __syncthreads();
    }
}

// ---- 128x128 f16 GEMM core, m97-style global_load_lds staging (r16) ----
__device__ __forceinline__ void gemm_core(
    const __half* __restrict__ A, const __half* __restrict__ Bt,
    const float* __restrict__ bias, void* __restrict__ dst,
    const int mode, const float oscale, const int m0, const int n0)
{
    __shared__ __align__(16) char gsm[34816];
    __half* Asl = (__half*)gsm;            // [128][64] linear
    __half* Bsl = (__half*)(gsm + 16384);  // [128][64] linear

    const int tid = threadIdx.x;
    const int lane = tid & 63, wv = tid >> 6;
    const int quad = lane >> 4, lr = lane & 15;
    const int wm0 = (wv >> 1) * 64, wn0 = (wv & 1) * 64;

    floatx4 acc[4][4];
    #pragma unroll
    for (int i = 0; i < 4; ++i)
        #pragma unroll
        for (int j = 0; j < 4; ++j)
            acc[i][j] = (floatx4){0.f, 0.f, 0.f, 0.f};

    const int rowb = wv * 32 + (lane >> 3);
    const int colb = (lane & 7) * 8;
    const __half* gA = A  + (size_t)(m0 + rowb) * D_ + colb;
    const __half* gB = Bt + (size_t)(n0 + rowb) * D_ + colb;

    for (int k0 = 0; k0 < D_; k0 += 64) {
        __syncthreads();                  // prior compute's LDS reads done
        #pragma unroll
        for (int p = 0; p < 4; ++p) {
            __builtin_amdgcn_global_load_lds(
                GLD_AS(gA + (size_t)p * 8 * D_),
                LDS_AS(gsm + (wv * 4 + p) * 1024), 16, 0, 0);
            __builtin_amdgcn_global_load_lds(
                GLD_AS(gB + (size_t)p * 8 * D_),
                LDS_AS(gsm + 16384 + (wv * 4 + p) * 1024), 16, 0, 0);
        }
        gA += 64; gB += 64;
        __syncthreads();                  // staged tile visible (vmcnt drained)

        __builtin_amdgcn_s_setprio(1);
        #pragma unroll
        for (int ks = 0; ks < 2; ++ks) {
            const int ko = quad * 8 + ks * 32;
            half8 af[4], bf[4];
            #pragma unroll
            for (int i = 0; i < 4; ++i)
                af[i] = *(const half8*)&Asl[(wm0 + i * 16 + lr) * 64 + ko];
            #pragma unroll
            for (int j = 0; j < 4; ++j)
                bf[j] = *(const half8*)&Bsl[(wn0 + j * 16 + lr) * 64 + ko];
            #pragma unroll
            for (int i = 0; i < 4; ++i)
                #pragma unroll
                for (int j = 0; j < 4; ++j)
                    acc[i][j] = MFMA32(af[i], bf[j], acc[i][j]);
        }
        __builtin_amdgcn_s_setprio(0);
    }

    if (mode == 1) {
        float* out = (float*)dst;
        #pragma unroll
        for (int i = 0; i < 4; ++i) {
            #pragma unroll
            for (int j = 0; j < 4; ++j) {
                const int col = n0 + wn0 + j * 16 + lr;
                const float bval = bias[col];
                #pragma unroll
                for (int r = 0; r < 4; ++r) {
                    const int m = m0 + wm0 + i * 16 + quad * 4 + r;
                    out[(size_t)m * D_ + col] = acc[i][j][r] + bval;
                }
            }
        }
        return;
    }

    // ---- LDS transpose epilogue (modes 0 and 2) ----
    __syncthreads();                      // all waves' staging reads done
    __half (*Ct)[136] = (__half(*)[136])gsm;
    #pragma unroll
    for (int i = 0; i < 4; ++i) {
        #pragma unroll
        for (int j = 0; j < 4; ++j) {
            const int nl = wn0 + j * 16 + lr;
            const float bval = bias[n0 + nl];
            #pragma unroll
            for (int r = 0; r < 4; ++r) {
                const int ml = wm0 + i * 16 + quad * 4 + r;
                const _Float16 hv = (_Float16)((acc[i][j][r] + bval) * oscale);
                if (mode == 0) Ct[ml][nl] = hv;
                else           Ct[nl][ml] = hv;
            }
        }
    }
    __syncthreads();
    __half* oh = (__half*)dst;
    #pragma unroll
    for (int p = 0; p < 8; ++p) {
        const int row = (tid >> 4) + p * 16;
        const int cs  = (tid & 15) * 8;
        const half8 vls = *(const half8*)&Ct[row][cs];
        if (mode == 0) {
            const int m = m0 + row, col = n0 + cs;
            const int b = m >> 11, s = m & (S_ - 1);
            const int h = col >> 6, d = col & 63;
            *(half8*)&oh[(((size_t)(b * H_ + h) * S_ + s) << 6) + d] = vls;
        } else {
            const int col = n0 + row, m = m0 + cs;
            const int b = m >> 11, s = m & (S_ - 1);
            const int h = col >> 6, d = col & 63;
            *(half8*)&oh[((size_t)(b * H_ + h) * DH_ + d) * S_ + s] = vls;
        }
    }
}

// z=0: Q (scatter, *0.125*log2e for exp2 softmax), z=1: K, z=2: V (transposed)
// XCD swizzle: grid (8,32,3)=768 blocks, 96/XCD contiguous (bijective).
__global__ __launch_bounds__(256) void gemm_proj(
    const __half* __restrict__ qf, const __half* __restrict__ kf,
    const __half* __restrict__ vf,
    const __half* __restrict__ Wtq, const __half* __restrict__ Wtk,
    const __half* __restrict__ Wtv,
    const float* __restrict__ bq, const float* __restrict__ bk,
    const float* __restrict__ bv,
    __half* __restrict__ qhf, __half* __restrict__ khf, __half* __restrict__ vht)
{
    const int flat = blockIdx.x + (blockIdx.y << 3) + (blockIdx.z << 8);
    const int wid = (flat & 7) * 96 + (flat >> 3);
    const int z = wid >> 8;
    const int rem = wid & 255;
    const int m0 = (rem >> 3) * 128, n0 = (rem & 7) * 128;

    const __half* As[3] = {qf, kf, vf};
    const __half* Bts[3] = {Wtq, Wtk, Wtv};
    const float* bs[3] = {bq, bk, bv};
    __half* ds[3] = {qhf, khf, vht};
    gemm_core(As[z], Bts[z], bs[z], ds[z], z == 2 ? 2 : 0,
              z == 0 ? 0.1803368801111244f : 1.0f, m0, n0);
}

// XCD swizzle: grid (8,32)=256 blocks, 32/XCD contiguous.
__global__ __launch_bounds__(256) void gemm_final(
    const __half* __restrict__ attf, const __half* __restrict__ Wto,
    const float* __restrict__ bo, float* __restrict__ out)
{
    const int flat = blockIdx.x + (blockIdx.y << 3);
    const int wid = (flat & 7) * 32 + (flat >> 3);
    const int m0 = (wid >> 3) * 128, n0 = (wid & 7) * 128;
    gemm_core(attf, Wto, bo, out, 1, 1.0f, m0, n0);
}

// ---- flash attention r20: gload_lds staging, T21 both-sides swizzle ----
// qhf/khf: [B,H,S,64] f16 (Q pre-scaled 0.125*log2e). vht: [B,H,64,S].
// 512 thr (8 waves = 2 kb x 4 qb), QBLK=128, KVBLK=64, dbuf 2x16KB:
// buf c: K 8KB @c*16384 (linear [64][64]), V 8KB @c*16384+8192.
// Staging: slot tid -> LDS byte tid*16; global src pre-shuffled seg^=(row&7)
// (16B granule). Reads XOR the same mask -> ~4-way conflicts (= old pad-72).
// Per tile: issue 2 gload_lds (t+1) at top, compute cur, single end barrier
// (drains vmcnt; worst case = m97 schedule, best case full overlap).
// XCD swizzle: grid (16,32)=512 blocks, 64/XCD.
__global__ __launch_bounds__(512, 4) void attn_f16(
    const __half* __restrict__ qhf, const __half* __restrict__ khf,
    const __half* __restrict__ vht, __half* __restrict__ attf)
{
    __shared__ __align__(16) char smem[36864];

    const int tid = threadIdx.x;
    const int lane = tid & 63, wv = tid >> 6;
    const int l31 = lane & 31, hi = lane >> 5;
    const int kb = wv >> 2, qb = wv & 3;
    const int flat = blockIdx.x + (blockIdx.y << 4);
    const int wid = ((flat & 7) << 6) + (flat >> 3);
    const int bh = wid >> 4;
    const int q0 = (wid & 15) * 128;
    const size_t hbase = (size_t)bh * S_ * DH_;

    // ---- Q B-frags [idx=q=l31][k(d)=hi*8+j] per 16-d slice, from global ----
    half8 qB[4];
    #pragma unroll
    for (int ds = 0; ds < 4; ++ds)
        qB[ds] = *(const half8*)&qhf[hbase
            + (size_t)(q0 + qb * 32 + l31) * DH_ + ds * 16 + hi * 8];

    float lp0 = 0.f, lp1 = 0.f;
#if !LP_FDOT2
    float lp2 = 0.f, lp3 = 0.f;
#endif
    floatx16 O[2];
    #pragma unroll
    for (int i = 0; i < 16; ++i) { O[0][i] = 0.f; O[1][i] = 0.f; }

    // ---- staging source (pre-shuffled per T21): slot tid covers LDS bytes
    // tid*16..+15; logical (row=tid>>3, seg=tid&7) stored with seg^=(row&7).
    const int srow = tid >> 3;
    const int sseg = (tid & 7) ^ (srow & 7);
    const __half* kg = khf + hbase + (size_t)srow * DH_ + sseg * 8;  // +=64*DH_
    const __half* vg = vht + hbase + (size_t)srow * S_ + sseg * 8;   // +=64

    // ---- swizzled read offsets (bytes within each 8KB buffer) ----
    // logical (r, 16B-block b) lives at byte r*128 + ((b ^ (r&7))<<4).
    int koff[4], voff[4];
    {
        const int m7 = l31 & 7;
        const int rK = (kb * 32 + l31) * 128;    // K read row = kb*32+l31
        #pragma unroll
        for (int ds = 0; ds < 4; ++ds)           // K 16B-block = ds*2+hi
            koff[ds] = rK + (((ds * 2 + hi) ^ m7) << 4);
        #pragma unroll
        for (int i = 0; i < 4; ++i) {            // V row = db*32+l31,
            const int db = i >> 1, ks = i & 1;   // block = kb*4+ks*2+hi
            voff[i] = (db * 32 + l31) * 128 + (((kb * 4 + ks * 2 + hi) ^ m7) << 4);
        }
    }

    // ---- prologue: stage tile 0 into buf0 ----
    __builtin_amdgcn_global_load_lds(GLD_AS(kg), LDS_AS(smem + wv * 1024), 16, 0, 0);
    __builtin_amdgcn_global_load_lds(GLD_AS(vg), LDS_AS(smem + 8192 + wv * 1024), 16, 0, 0);
    kg += 64 * DH_; vg += 64;
    __syncthreads();                       // tile 0 visible (vmcnt drained)

    const half2v one2 = {(_Float16)1.0f, (_Float16)1.0f};

    for (int kt = 0; kt < S_; kt += 64) {
        const int cb = (kt >> 6) & 1;
        char* cur = smem + cb * 16384;
        char* nxt = smem + (cb ^ 1) * 16384;

        // issue t+1 loads into the other buffer (post-barrier: safe)
        if (kt + 64 < S_) {
            __builtin_amdgcn_global_load_lds(GLD_AS(kg), LDS_AS(nxt + wv * 1024), 16, 0, 0);
            __builtin_amdgcn_global_load_lds(GLD_AS(vg), LDS_AS(nxt + 8192 + wv * 1024), 16, 0, 0);
            kg += 64 * DH_; vg += 64;
        }

        // ---- S^T = K Q^T : 32k (band kb) x 32q (band qb), K-dim = d ----
        floatx16 s;
        #pragma unroll
        for (int i = 0; i < 16; ++i) s[i] = 0.f;
        __builtin_amdgcn_s_setprio(1);
        #pragma unroll
        for (int ds = 0; ds < 4; ++ds) {
            const half8 aK = *(const half8*)(cur + koff[ds]);
            s = MFMA3216(aK, qB[ds], s);
        }
        __builtin_amdgcn_s_setprio(0);

        // ---- P^T = exp2(S^T) ----
        #pragma unroll
        for (int r = 0; r < 16; ++r) {
            const float e = __builtin_amdgcn_exp2f(s[r]);
#if !LP_FDOT2
            (r & 2) ? ((r & 1) ? (lp3 += e) : (lp2 += e))
                    : ((r & 1) ? (lp1 += e) : (lp0 += e));
#endif
            s[r] = e;
        }

        // ---- pack to PV B-frags [idx=q][k=hi*8+j] per 16-k slice ----
        half8 pB[2];
        int PW[2][4];
        #pragma unroll
        for (int ks = 0; ks < 2; ++ks) {
            int P0 = __builtin_bit_cast(int, __builtin_amdgcn_cvt_pkrtz(s[ks * 8 + 0], s[ks * 8 + 1]));
            int P1 = __builtin_bit_cast(int, __builtin_amdgcn_cvt_pkrtz(s[ks * 8 + 2], s[ks * 8 + 3]));
            int P2 = __builtin_bit_cast(int, __builtin_amdgcn_cvt_pkrtz(s[ks * 8 + 4], s[ks * 8 + 5]));
            int P3 = __builtin_bit_cast(int, __builtin_amdgcn_cvt_pkrtz(s[ks * 8 + 6], s[ks * 8 + 7]));
            half_swap(P0, P2, hi);
            half_swap(P1, P3, hi);
            PW[ks][0] = P0; PW[ks][1] = P1; PW[ks][2] = P2; PW[ks][3] = P3;
            const intx4 w = {P0, P1, P2, P3};
            pB[ks] = __builtin_bit_cast(half8, w);
        }

        // ---- O^T += V^T P^T over wave's 32-k band ----
        __builtin_amdgcn_s_setprio(1);
        #pragma unroll
        for (int db = 0; db < 2; ++db)
            #pragma unroll
            for (int ks = 0; ks < 2; ++ks) {
                const half8 aV = *(const half8*)(cur + 8192 + voff[db * 2 + ks]);
                O[db] = MFMA3216(aV, pB[ks], O[db]);
            }
        __builtin_amdgcn_s_setprio(0);

#if LP_FDOT2
        // ---- lp row-sum from packed P (MFMA pipe busy window) ----
        #pragma unroll
        for (int ks = 0; ks < 2; ++ks) {
            lp0 = __builtin_amdgcn_fdot2(__builtin_bit_cast(half2v, PW[ks][0]), one2, lp0, false);
            lp1 = __builtin_amdgcn_fdot2(__builtin_bit_cast(half2v, PW[ks][1]), one2, lp1, false);
            lp0 = __builtin_amdgcn_fdot2(__builtin_bit_cast(half2v, PW[ks][2]), one2, lp0, false);
            lp1 = __builtin_amdgcn_fdot2(__builtin_bit_cast(half2v, PW[ks][3]), one2, lp1, false);
        }
#endif

        __syncthreads();   // drains t+1 loads; cur reads done before overwrite
    }

    // ---- epilogue: 2-way k-band reduce + softmax normalize, 128 q rows ----
    float (*R)[132] = (float(*)[132])smem;            // [64 d][128 q(+4)] f32
    float* Lred = (float*)(smem + 33792);             // [2][128] f32

#if LP_FDOT2
    float lp = lp0 + lp1;
#else
    float lp = (lp0 + lp1) + (lp2 + lp3);
#endif
    lp += __shfl_xor(lp, 32, 64);                     // combine hi/lo (same q)
    const int qg = qb * 32 + l31;
    if (lane < 32) Lred[kb * 128 + qg] = lp;
    if (kb == 1) {
        #pragma unroll
        for (int db = 0; db < 2; ++db)
            #pragma unroll
            for (int r = 0; r < 16; ++r) {
                const int d = db * 32 + (r & 3) + 8 * (r >> 2) + 4 * hi;
                R[d][qg] = O[db][r];
            }
    }
    __syncthreads();
    if (kb == 0) {
        const float il = 1.0f / (Lred[qg] + Lred[128 + qg]);
        #pragma unroll
        for (int db = 0; db < 2; ++db)
            #pragma unroll
            for (int r = 0; r < 16; ++r) {
                const int d = db * 32 + (r & 3) + 8 * (r >> 2) + 4 * hi;
                O[db][r] = (O[db][r] + R[d][qg]) * il;
            }
    }
    __syncthreads();
    __half (*F)[72] = (__half(*)[72])smem;            // [128 q][64 d] f16
    if (kb == 0) {
        #pragma unroll
        for (int db = 0; db < 2; ++db)
            #pragma unroll
            for (int t = 0; t < 4; ++t) {
                half4 hv;
                #pragma unroll
                for (int r = 0; r < 4; ++r) hv[r] = (_Float16)O[db][t * 4 + r];
                *(half4*)&F[qg][db * 32 + t * 8 + hi * 4] = hv;
            }
    }
    __syncthreads();

    const int b = bh >> 4, h = bh & 15;
    const int qrow = tid >> 2, dseg = (tid & 3) * 16;
    __half* dstp = &attf[(((size_t)(b * S_ + q0 + qrow)) << 10) + h * DH_ + dseg];
    *(half8*)&dstp[0] = *(const half8*)&F[qrow][dseg];
    *(half8*)&dstp[8] = *(const half8*)&F[qrow][dseg + 8];
}

extern "C" void kernel_launch(void* const* d_in, const int* in_sizes, int n_in,
                              void* d_out, int out_size, void* d_ws, size_t ws_size,
                              hipStream_t stream) {
    const float* q  = (const float*)d_in[0];
    const float* k  = (const float*)d_in[1];
    const float* v  = (const float*)d_in[2];
    const float* Wq = (const float*)d_in[3];
    const float* bq = (const float*)d_in[4];
    const float* Wk = (const float*)d_in[5];
    const float* bk = (const float*)d_in[6];
    const float* Wv = (const float*)d_in[7];
    const float* bv = (const float*)d_in[8];
    const float* Wo = (const float*)d_in[9];
    const float* bo = (const float*)d_in[10];
    float* out = (float*)d_out;

    __half* ws = (__half*)d_ws;
    const size_t NE = (size_t)B_ * S_ * D_;     // 4,194,304
    __half* qf   = ws;
    __half* kf   = ws + NE;
    __half* vf   = ws + 2 * NE;
    __half* qhf  = ws + 3 * NE;
    __half* khf  = ws + 4 * NE;
    __half* vht  = ws + 5 * NE;
    __half* attf = ws + 6 * NE;
    __half* Wtq  = ws + 7 * NE;
    __half* Wtk  = Wtq + (size_t)D_ * D_;
    __half* Wtv  = Wtk + (size_t)D_ * D_;
    __half* Wto  = Wtv + (size_t)D_ * D_;

    const dim3 blk(256);
    prep<<<dim3((unsigned)(NE / 8 / 256), 1, 4), blk, 0, stream>>>(
        q, k, v, qf, kf, vf, Wq, Wk, Wv, Wo, Wtq, Wtk, Wtv, Wto);

    gemm_proj<<<dim3(D_ / 128, (B_ * S_) / 128, 3), blk, 0, stream>>>(
        qf, kf, vf, Wtq, Wtk, Wtv, bq, bk, bv, qhf, khf, vht);

    attn_f16<<<dim3(S_ / 128, B_ * H_), dim3(512), 0, stream>>>(qhf, khf, vht, attf);

    gemm_final<<<dim3(D_ / 128, (B_ * S_) / 128), blk, 0, stream>>>(attf, Wto, bo, out);
}

// Round 13
// 222.424 us; speedup vs baseline: 1.0686x; 1.0136x over previous
//
#include <hip/hip_runtime.h>
#include <hip/hip_fp16.h>
#include <cstddef>

// ---------------------------------------------------------------------------
// CrossAttention, f16 MFMA, round 21.
//   B=2, Sq=Sk=2048, D=1024, H=16, Dh=64
// r20 post-mortem: attn T21-swizzle staging refcheck-passed but time-neutral;
// reverted attn to r16 (known 46.8us). NEW signal from r20 counters:
// gemm LDS_Block_Size 34816 -> 4 blocks/CU (163840/34816); the overflow is
// the epilogue overlay Ct[128][136], not the 32KB staging. r21: shrink
// gemm_core LDS to exactly 32768 (5 blocks/CU; VGPR 76 << 102 cap) via a
// two-pass mode-0/2 epilogue: pass p writes/drains the N-half owned by waves
// with wn0==p*64 (Ct0[128][68] / Ct2[64][136], 17408B each). Staging loop
// byte-identical to r16. m132 evidence: 2-phase loop is strongly
// occupancy-sensitive -> +1 block/CU should cut the barrier-drain stall.
// Layouts (32x32x16): A/B [idx=lane&31][k=(lane>>5)*8+j];
//   C/D col=lane&31, row=(reg&3)+8*(reg>>2)+4*(lane>>5)  [m74/m101].
// P repack: P0=pk(s0,s1) P1=pk(s2,s3) P2=pk(s4,s5) P3=pk(s6,s7);
//   swap(P0,P2), swap(P1,P3) -> B-frag words [P0,P1,P2,P3]. (r13-verified)
// ---------------------------------------------------------------------------

#define B_   2
#define S_   2048
#define D_   1024
#define H_   16
#define DH_  64

typedef _Float16 half8 __attribute__((ext_vector_type(8)));
typedef _Float16 half4 __attribute__((ext_vector_type(4)));
typedef _Float16 half2v __attribute__((ext_vector_type(2)));
typedef float floatx4 __attribute__((ext_vector_type(4)));
typedef float floatx16 __attribute__((ext_vector_type(16)));
typedef int intx4 __attribute__((ext_vector_type(4)));

#define MFMA32(a, b, c) __builtin_amdgcn_mfma_f32_16x16x32_f16((a), (b), (c), 0, 0, 0)
#define MFMA3216(a, b, c) __builtin_amdgcn_mfma_f32_32x32x16_f16((a), (b), (c), 0, 0, 0)

#if __has_builtin(__builtin_amdgcn_fdot2)
#define LP_FDOT2 1
#else
#define LP_FDOT2 0
#endif

#define GLD_AS(p) ((const __attribute__((address_space(1))) void*)(p))
#define LDS_AS(p) ((__attribute__((address_space(3))) void*)(p))

// exchange: newA = {A.lo32, B.lo32}, newB = {A.hi32, B.hi32}
__device__ __forceinline__ void half_swap(int& a, int& b, const int hi) {
#if __has_builtin(__builtin_amdgcn_permlane32_swap)
    (void)hi;
    auto r = __builtin_amdgcn_permlane32_swap(a, b, false, false);
    a = r[0]; b = r[1];
#else
    const int ax = __shfl_xor(a, 32, 64), bx = __shfl_xor(b, 32, 64);
    const int na = hi ? bx : a;
    b = hi ? b : ax;
    a = na;
#endif
}

// ---- fused: fp32->f16 cvt for q/k/v (z<3) + W transpose x4 (z==3) ----
__global__ __launch_bounds__(256) void prep(
    const float* __restrict__ q, const float* __restrict__ k,
    const float* __restrict__ v,
    __half* __restrict__ qf, __half* __restrict__ kf, __half* __restrict__ vf,
    const float* __restrict__ Wq, const float* __restrict__ Wk,
    const float* __restrict__ Wv, const float* __restrict__ Wo,
    __half* __restrict__ Wtq, __half* __restrict__ Wtk,
    __half* __restrict__ Wtv, __half* __restrict__ Wto)
{
    __shared__ __align__(16) __half T[64][72];
    const int tid = threadIdx.x;
    const int z = blockIdx.z;
    if (z < 3) {
        const float* srcs[3] = {q, k, v};
        __half* dsts[3] = {qf, kf, vf};
        const int i = blockIdx.x * 256 + tid;
        const float4* s = (const float4*)srcs[z];
        const float4 a = s[2 * i], b = s[2 * i + 1];
        half8 h;
        h[0] = (_Float16)a.x; h[1] = (_Float16)a.y; h[2] = (_Float16)a.z; h[3] = (_Float16)a.w;
        h[4] = (_Float16)b.x; h[5] = (_Float16)b.y; h[6] = (_Float16)b.z; h[7] = (_Float16)b.w;
        *(half8*)&dsts[z][(size_t)i * 8] = h;
        return;
    }
    if (blockIdx.x >= 256) return;
    const float* Ws[4] = {Wq, Wk, Wv, Wo};
    __half* Wts[4] = {Wtq, Wtk, Wtv, Wto};
    const int n0 = (blockIdx.x & 15) * 64, k0 = (blockIdx.x >> 4) * 64;
    for (int w = 0; w < 4; ++w) {
        const float* W = Ws[w];
        __half* Wt = Wts[w];
        #pragma unroll
        for (int p = 0; p < 4; ++p) {
            const int c = tid + p * 256;
            const int kr = c >> 4, nc = (c & 15) * 4;
            const float4 a = *(const float4*)&W[(size_t)(k0 + kr) * D_ + n0 + nc];
            T[nc + 0][kr] = __float2half(a.x);
            T[nc + 1][kr] = __float2half(a.y);
            T[nc + 2][kr] = __float2half(a.z);
            T[nc + 3][kr] = __float2half(a.w);
        }
        __syncthreads();
        #pragma unroll
        for (int p = 0; p < 2; ++p) {
            const int c = tid + p * 256;
            const int nr = c >> 3, kc = (c & 7) * 8;
            *(half8*)&Wt[(size_t)(n0 + nr) * D_ + k0 + kc] = *(const half8*)&T[nr][kc];
        }
        __syncthreads();
    }
}

// ---- 128x128 f16 GEMM core, m97-style global_load_lds staging (r16) ----
// r21: LDS exactly 32768B (staging 2x16KB linear; epilogue overlays fit
// 17408B) -> 5 blocks/CU (was 4 at 34816B). Two-pass mode-0/2 epilogue.
// mode 0: dst f16 scatter [B,H,S,Dh] * oscale; mode 1: fp32 [M][1024];
// mode 2: f16 transposed [B,H,Dh,S].
__device__ __forceinline__ void gemm_core(
    const __half* __restrict__ A, const __half* __restrict__ Bt,
    const float* __restrict__ bias, void* __restrict__ dst,
    const int mode, const float oscale, const int m0, const int n0)
{
    __shared__ __align__(16) char gsm[32768];
    __half* Asl = (__half*)gsm;            // [128][64] linear
    __half* Bsl = (__half*)(gsm + 16384);  // [128][64] linear

    const int tid = threadIdx.x;
    const int lane = tid & 63, wv = tid >> 6;
    const int quad = lane >> 4, lr = lane & 15;
    const int wm0 = (wv >> 1) * 64, wn0 = (wv & 1) * 64;

    floatx4 acc[4][4];
    #pragma unroll
    for (int i = 0; i < 4; ++i)
        #pragma unroll
        for (int j = 0; j < 4; ++j)
            acc[i][j] = (floatx4){0.f, 0.f, 0.f, 0.f};

    const int rowb = wv * 32 + (lane >> 3);
    const int colb = (lane & 7) * 8;
    const __half* gA = A  + (size_t)(m0 + rowb) * D_ + colb;
    const __half* gB = Bt + (size_t)(n0 + rowb) * D_ + colb;

    for (int k0 = 0; k0 < D_; k0 += 64) {
        __syncthreads();                  // prior compute's LDS reads done
        #pragma unroll
        for (int p = 0; p < 4; ++p) {
            __builtin_amdgcn_global_load_lds(
                GLD_AS(gA + (size_t)p * 8 * D_),
                LDS_AS(gsm + (wv * 4 + p) * 1024), 16, 0, 0);
            __builtin_amdgcn_global_load_lds(
                GLD_AS(gB + (size_t)p * 8 * D_),
                LDS_AS(gsm + 16384 + (wv * 4 + p) * 1024), 16, 0, 0);
        }
        gA += 64; gB += 64;
        __syncthreads();                  // staged tile visible (vmcnt drained)

        __builtin_amdgcn_s_setprio(1);
        #pragma unroll
        for (int ks = 0; ks < 2; ++ks) {
            const int ko = quad * 8 + ks * 32;
            half8 af[4], bf[4];
            #pragma unroll
            for (int i = 0; i < 4; ++i)
                af[i] = *(const half8*)&Asl[(wm0 + i * 16 + lr) * 64 + ko];
            #pragma unroll
            for (int j = 0; j < 4; ++j)
                bf[j] = *(const half8*)&Bsl[(wn0 + j * 16 + lr) * 64 + ko];
            #pragma unroll
            for (int i = 0; i < 4; ++i)
                #pragma unroll
                for (int j = 0; j < 4; ++j)
                    acc[i][j] = MFMA32(af[i], bf[j], acc[i][j]);
        }
        __builtin_amdgcn_s_setprio(0);
    }

    if (mode == 1) {
        float* out = (float*)dst;
        #pragma unroll
        for (int i = 0; i < 4; ++i) {
            #pragma unroll
            for (int j = 0; j < 4; ++j) {
                const int col = n0 + wn0 + j * 16 + lr;
                const float bval = bias[col];
                #pragma unroll
                for (int r = 0; r < 4; ++r) {
                    const int m = m0 + wm0 + i * 16 + quad * 4 + r;
                    out[(size_t)m * D_ + col] = acc[i][j][r] + bval;
                }
            }
        }
        return;
    }

    // ---- two-pass LDS transpose epilogue (modes 0 and 2) ----
    // pass p drains the N-half owned by waves with wn0 == p*64.
    __half (*Ct0)[68]  = (__half(*)[68])gsm;    // mode 0: [128 m][64+4 n]
    __half (*Ct2)[136] = (__half(*)[136])gsm;   // mode 2: [64 n][128+8 m]
    __half* oh = (__half*)dst;
    #pragma unroll
    for (int pass = 0; pass < 2; ++pass) {
        __syncthreads();                  // staging/prev-pass reads done
        if ((wv & 1) == pass) {
            #pragma unroll
            for (int i = 0; i < 4; ++i) {
                #pragma unroll
                for (int j = 0; j < 4; ++j) {
                    const int nl = j * 16 + lr;            // col within half
                    const float bval = bias[n0 + pass * 64 + nl];
                    #pragma unroll
                    for (int r = 0; r < 4; ++r) {
                        const int ml = wm0 + i * 16 + quad * 4 + r;
                        const _Float16 hv = (_Float16)((acc[i][j][r] + bval) * oscale);
                        if (mode == 0) Ct0[ml][nl] = hv;
                        else           Ct2[nl][ml] = hv;
                    }
                }
            }
        }
        __syncthreads();
        if (mode == 0) {
            #pragma unroll
            for (int p = 0; p < 4; ++p) {
                const int row = (tid >> 3) + p * 32;       // 0..127 (m)
                const int cs  = (tid & 7) * 8;             // 0..56  (n)
                const half8 vls = *(const half8*)&Ct0[row][cs];
                const int m = m0 + row, col = n0 + pass * 64 + cs;
                const int b = m >> 11, s = m & (S_ - 1);
                const int h = col >> 6, d = col & 63;
                *(half8*)&oh[(((size_t)(b * H_ + h) * S_ + s) << 6) + d] = vls;
            }
        } else {
            #pragma unroll
            for (int p = 0; p < 4; ++p) {
                const int row = (tid >> 4) + p * 16;       // 0..63 (n local)
                const int cs  = (tid & 15) * 8;            // 0..120 (m)
                const half8 vls = *(const half8*)&Ct2[row][cs];
                const int col = n0 + pass * 64 + row, m = m0 + cs;
                const int b = m >> 11, s = m & (S_ - 1);
                const int h = col >> 6, d = col & 63;
                *(half8*)&oh[((size_t)(b * H_ + h) * DH_ + d) * S_ + s] = vls;
            }
        }
    }
}

// z=0: Q (scatter, *0.125*log2e for exp2 softmax), z=1: K, z=2: V (transposed)
// XCD swizzle: grid (8,32,3)=768 blocks, 96/XCD contiguous (bijective).
__global__ __launch_bounds__(256) void gemm_proj(
    const __half* __restrict__ qf, const __half* __restrict__ kf,
    const __half* __restrict__ vf,
    const __half* __restrict__ Wtq, const __half* __restrict__ Wtk,
    const __half* __restrict__ Wtv,
    const float* __restrict__ bq, const float* __restrict__ bk,
    const float* __restrict__ bv,
    __half* __restrict__ qhf, __half* __restrict__ khf, __half* __restrict__ vht)
{
    const int flat = blockIdx.x + (blockIdx.y << 3) + (blockIdx.z << 8);
    const int wid = (flat & 7) * 96 + (flat >> 3);
    const int z = wid >> 8;
    const int rem = wid & 255;
    const int m0 = (rem >> 3) * 128, n0 = (rem & 7) * 128;

    const __half* As[3] = {qf, kf, vf};
    const __half* Bts[3] = {Wtq, Wtk, Wtv};
    const float* bs[3] = {bq, bk, bv};
    __half* ds[3] = {qhf, khf, vht};
    gemm_core(As[z], Bts[z], bs[z], ds[z], z == 2 ? 2 : 0,
              z == 0 ? 0.1803368801111244f : 1.0f, m0, n0);
}

// XCD swizzle: grid (8,32)=256 blocks, 32/XCD contiguous.
__global__ __launch_bounds__(256) void gemm_final(
    const __half* __restrict__ attf, const __half* __restrict__ Wto,
    const float* __restrict__ bo, float* __restrict__ out)
{
    const int flat = blockIdx.x + (blockIdx.y << 3);
    const int wid = (flat & 7) * 32 + (flat >> 3);
    const int m0 = (wid >> 3) * 128, n0 = (wid & 7) * 128;
    gemm_core(attf, Wto, bo, out, 1, 1.0f, m0, n0);
}

// ---- flash attention (r16 structure, best measured 46.8us) ----
// 32x32 MFMA, QBLK=128, 512 threads (8 waves = 2 kb x 4 qb), KVBLK=64,
// double-buffered LDS. qhf/khf: [B,H,S,64] f16 (Q pre-scaled 0.125*log2e).
// vht: [B,H,64,S]. XCD swizzle: grid (16,32)=512 blocks, 64/XCD.
__global__ __launch_bounds__(512, 4) void attn_f16(
    const __half* __restrict__ qhf, const __half* __restrict__ khf,
    const __half* __restrict__ vht, __half* __restrict__ attf)
{
    __shared__ __align__(16) char smem[36864];

    const int tid = threadIdx.x;
    const int lane = tid & 63, wv = tid >> 6;
    const int l31 = lane & 31, hi = lane >> 5;
    const int kb = wv >> 2, qb = wv & 3;
    const int flat = blockIdx.x + (blockIdx.y << 4);
    const int wid = ((flat & 7) << 6) + (flat >> 3);
    const int bh = wid >> 4;
    const int q0 = (wid & 15) * 128;
    const size_t hbase = (size_t)bh * S_ * DH_;

    // ---- Q B-frags [idx=q=l31][k(d)=hi*8+j] per 16-d slice, from global ----
    half8 qB[4];
    #pragma unroll
    for (int ds = 0; ds < 4; ++ds)
        qB[ds] = *(const half8*)&qhf[hbase
            + (size_t)(q0 + qb * 32 + l31) * DH_ + ds * 16 + hi * 8];

    float lp0 = 0.f, lp1 = 0.f;
#if !LP_FDOT2
    float lp2 = 0.f, lp3 = 0.f;
#endif
    floatx16 O[2];
    #pragma unroll
    for (int i = 0; i < 16; ++i) { O[0][i] = 0.f; O[1][i] = 0.f; }

    // ---- staging mapping (512 thr): one K + one V half8 per thread ----
    const int srow = tid >> 3, sseg = (tid & 7) * 8;
    const __half* kg = khf + hbase + (size_t)srow * DH_ + sseg;  // += 64*DH_/tile
    const __half* vg = vht + hbase + (size_t)srow * S_ + sseg;   // += 64/tile

    // ---- stage tile 0 directly into buf0 ----
    {
        __half (*K0)[72] = (__half(*)[72])smem;
        __half (*V0)[72] = (__half(*)[72])(smem + 9216);
        *(half8*)&K0[srow][sseg] = *(const half8*)kg;
        *(half8*)&V0[srow][sseg] = *(const half8*)vg;
    }
    // ---- prefetch tile 1 into registers ----
    kg += 64 * DH_; vg += 64;
    half8 pk = *(const half8*)kg;
    half8 pv = *(const half8*)vg;
    __syncthreads();                       // tile 0 visible

    const half2v one2 = {(_Float16)1.0f, (_Float16)1.0f};

    for (int kt = 0; kt < S_; kt += 64) {
        const int cb = (kt >> 6) & 1;
        __half (*Ks)[72] = (__half(*)[72])(smem + cb * 18432);
        __half (*Vs)[72] = (__half(*)[72])(smem + cb * 18432 + 9216);
        __half (*Kn)[72] = (__half(*)[72])(smem + (cb ^ 1) * 18432);
        __half (*Vn)[72] = (__half(*)[72])(smem + (cb ^ 1) * 18432 + 9216);

        // write tile t+1 into the other buffer (overlaps compute reads)
        if (kt + 64 < S_) {
            *(half8*)&Kn[srow][sseg] = pk;
            *(half8*)&Vn[srow][sseg] = pv;
            if (kt + 128 < S_) {           // issue t+2 loads; fly during compute
                kg += 64 * DH_; vg += 64;
                pk = *(const half8*)kg;
                pv = *(const half8*)vg;
            }
        }

        // ---- S^T = K Q^T : 32k (band kb) x 32q (band qb), K-dim = d ----
        floatx16 s;
        #pragma unroll
        for (int i = 0; i < 16; ++i) s[i] = 0.f;
        __builtin_amdgcn_s_setprio(1);
        #pragma unroll
        for (int ds = 0; ds < 4; ++ds) {
            const half8 aK = *(const half8*)&Ks[kb * 32 + l31][ds * 16 + hi * 8];
            s = MFMA3216(aK, qB[ds], s);
        }
        __builtin_amdgcn_s_setprio(0);

        // ---- P^T = exp2(S^T) ----
        #pragma unroll
        for (int r = 0; r < 16; ++r) {
            const float e = __builtin_amdgcn_exp2f(s[r]);
#if !LP_FDOT2
            (r & 2) ? ((r & 1) ? (lp3 += e) : (lp2 += e))
                    : ((r & 1) ? (lp1 += e) : (lp0 += e));
#endif
            s[r] = e;
        }

        // ---- pack to PV B-frags [idx=q][k=hi*8+j] per 16-k slice ----
        half8 pB[2];
        int PW[2][4];
        #pragma unroll
        for (int ks = 0; ks < 2; ++ks) {
            int P0 = __builtin_bit_cast(int, __builtin_amdgcn_cvt_pkrtz(s[ks * 8 + 0], s[ks * 8 + 1]));
            int P1 = __builtin_bit_cast(int, __builtin_amdgcn_cvt_pkrtz(s[ks * 8 + 2], s[ks * 8 + 3]));
            int P2 = __builtin_bit_cast(int, __builtin_amdgcn_cvt_pkrtz(s[ks * 8 + 4], s[ks * 8 + 5]));
            int P3 = __builtin_bit_cast(int, __builtin_amdgcn_cvt_pkrtz(s[ks * 8 + 6], s[ks * 8 + 7]));
            half_swap(P0, P2, hi);
            half_swap(P1, P3, hi);
            PW[ks][0] = P0; PW[ks][1] = P1; PW[ks][2] = P2; PW[ks][3] = P3;
            const intx4 w = {P0, P1, P2, P3};
            pB[ks] = __builtin_bit_cast(half8, w);
        }

        // ---- O^T += V^T P^T over wave's 32-k band ----
        __builtin_amdgcn_s_setprio(1);
        #pragma unroll
        for (int db = 0; db < 2; ++db)
            #pragma unroll
            for (int ks = 0; ks < 2; ++ks) {
                const half8 aV = *(const half8*)&Vs[db * 32 + l31][kb * 32 + ks * 16 + hi * 8];
                O[db] = MFMA3216(aV, pB[ks], O[db]);
            }
        __builtin_amdgcn_s_setprio(0);

#if LP_FDOT2
        // ---- lp row-sum from packed P (MFMA pipe busy window) ----
        #pragma unroll
        for (int ks = 0; ks < 2; ++ks) {
            lp0 = __builtin_amdgcn_fdot2(__builtin_bit_cast(half2v, PW[ks][0]), one2, lp0, false);
            lp1 = __builtin_amdgcn_fdot2(__builtin_bit_cast(half2v, PW[ks][1]), one2, lp1, false);
            lp0 = __builtin_amdgcn_fdot2(__builtin_bit_cast(half2v, PW[ks][2]), one2, lp0, false);
            lp1 = __builtin_amdgcn_fdot2(__builtin_bit_cast(half2v, PW[ks][3]), one2, lp1, false);
        }
#endif

        __syncthreads();   // t+1 writes visible; buf reads done before t+2 overwrite
    }

    // ---- epilogue: 2-way k-band reduce + softmax normalize, 128 q rows ----
    float (*R)[132] = (float(*)[132])smem;            // [64 d][128 q(+4)] f32
    float* Lred = (float*)(smem + 33792);             // [2][128] f32

#if LP_FDOT2
    float lp = lp0 + lp1;
#else
    float lp = (lp0 + lp1) + (lp2 + lp3);
#endif
    lp += __shfl_xor(lp, 32, 64);                     // combine hi/lo (same q)
    const int qg = qb * 32 + l31;
    if (lane < 32) Lred[kb * 128 + qg] = lp;
    if (kb == 1) {
        #pragma unroll
        for (int db = 0; db < 2; ++db)
            #pragma unroll
            for (int r = 0; r < 16; ++r) {
                const int d = db * 32 + (r & 3) + 8 * (r >> 2) + 4 * hi;
                R[d][qg] = O[db][r];
            }
    }
    __syncthreads();
    if (kb == 0) {
        const float il = 1.0f / (Lred[qg] + Lred[128 + qg]);
        #pragma unroll
        for (int db = 0; db < 2; ++db)
            #pragma unroll
            for (int r = 0; r < 16; ++r) {
                const int d = db * 32 + (r & 3) + 8 * (r >> 2) + 4 * hi;
                O[db][r] = (O[db][r] + R[d][qg]) * il;
            }
    }
    __syncthreads();
    __half (*F)[72] = (__half(*)[72])smem;            // [128 q][64 d] f16
    if (kb == 0) {
        #pragma unroll
        for (int db = 0; db < 2; ++db)
            #pragma unroll
            for (int t = 0; t < 4; ++t) {
                half4 hv;
                #pragma unroll
                for (int r = 0; r < 4; ++r) hv[r] = (_Float16)O[db][t * 4 + r];
                *(half4*)&F[qg][db * 32 + t * 8 + hi * 4] = hv;
            }
    }
    __syncthreads();

    const int b = bh >> 4, h = bh & 15;
    const int qrow = tid >> 2, dseg = (tid & 3) * 16;
    __half* dstp = &attf[(((size_t)(b * S_ + q0 + qrow)) << 10) + h * DH_ + dseg];
    *(half8*)&dstp[0] = *(const half8*)&F[qrow][dseg];
    *(half8*)&dstp[8] = *(const half8*)&F[qrow][dseg + 8];
}

extern "C" void kernel_launch(void* const* d_in, const int* in_sizes, int n_in,
                              void* d_out, int out_size, void* d_ws, size_t ws_size,
                              hipStream_t stream) {
    const float* q  = (const float*)d_in[0];
    const float* k  = (const float*)d_in[1];
    const float* v  = (const float*)d_in[2];
    const float* Wq = (const float*)d_in[3];
    const float* bq = (const float*)d_in[4];
    const float* Wk = (const float*)d_in[5];
    const float* bk = (const float*)d_in[6];
    const float* Wv = (const float*)d_in[7];
    const float* bv = (const float*)d_in[8];
    const float* Wo = (const float*)d_in[9];
    const float* bo = (const float*)d_in[10];
    float* out = (float*)d_out;

    __half* ws = (__half*)d_ws;
    const size_t NE = (size_t)B_ * S_ * D_;     // 4,194,304
    __half* qf   = ws;
    __half* kf   = ws + NE;
    __half* vf   = ws + 2 * NE;
    __half* qhf  = ws + 3 * NE;
    __half* khf  = ws + 4 * NE;
    __half* vht  = ws + 5 * NE;
    __half* attf = ws + 6 * NE;
    __half* Wtq  = ws + 7 * NE;
    __half* Wtk  = Wtq + (size_t)D_ * D_;
    __half* Wtv  = Wtk + (size_t)D_ * D_;
    __half* Wto  = Wtv + (size_t)D_ * D_;

    const dim3 blk(256);
    prep<<<dim3((unsigned)(NE / 8 / 256), 1, 4), blk, 0, stream>>>(
        q, k, v, qf, kf, vf, Wq, Wk, Wv, Wo, Wtq, Wtk, Wtv, Wto);

    gemm_proj<<<dim3(D_ / 128, (B_ * S_) / 128, 3), blk, 0, stream>>>(
        qf, kf, vf, Wtq, Wtk, Wtv, bq, bk, bv, qhf, khf, vht);

    attn_f16<<<dim3(S_ / 128, B_ * H_), dim3(512), 0, stream>>>(qhf, khf, vht, attf);

    gemm_final<<<dim3(D_ / 128, (B_ * S_) / 128), blk, 0, stream>>>(attf, Wto, bo, out);
}